// Round 3
// baseline (146.700 us; speedup 1.0000x reference)
//
#include <hip/hip_runtime.h>
#include <hip/hip_bf16.h>
#include <cstddef>

// B=16, N=512, C_SIZE=512, STRIDE=8 -> C=64, M=4096, out [16, 513, 4096] fp32.
constexpr int NPT = 512;
constexpr int C   = 64;
constexpr int M   = C * C;          // 4096
constexpr int NP1 = NPT + 1;        // 513
constexpr float BG_RATIO = 0.15f;
constexpr float EPS = 1e-5f;
// exp(-d/128) == exp2(d * CEXP), CEXP = -log2(e)/128
constexpr float CEXP = -0.011271055f;

// ---------------- Kernel 1: per-pixel softmax denominators ----------------
// Block = 256 threads per (b, i) row of 64 pixels. Thread t: jg=t&15 owns
// pixels 4*jg..4*jg+3, pc=t>>4 owns points [32*pc, 32*pc+32).
// Fused min-dist + exp-sum (no max-shift needed: logits <= 0 and
// min(mind,bg) <= (0.15*512)^2 -> denom >= exp2(76.8^2*CEXP) ~ 1e-20, safe fp32;
// verified vs np ref in R2, absmax 3e-5).
// Writes rs[b][4096] (reciprocal denom) to workspace + the background row.
__global__ __launch_bounds__(256) void pp_denom(
    const float* __restrict__ points,   // [B, NPT, 2]
    const float* __restrict__ st,       // [B]
    float* __restrict__ out,            // [B, NP1, M] (bg row only)
    float* __restrict__ rsws)           // [B, M] workspace
{
    const int b    = blockIdx.x >> 6;
    const int i    = blockIdx.x & 63;
    const int t    = threadIdx.x;
    const int lane = t & 63;
    const int w    = t >> 6;
    const int jg   = t & 15;
    const int pc   = t >> 4;

    const float cy  = (float)(i * 8 + 4);
    const float cx0 = (float)(jg * 32 + 4);
    const float cx1 = cx0 + 8.0f;
    const float cx2 = cx0 + 16.0f;
    const float cx3 = cx0 + 24.0f;

    __shared__ float2 pts[NPT];          // 4 KB
    __shared__ float4 redmin[4][16];     // [wave][jg]
    __shared__ float4 redsum[4][16];

    const float2* pb = (const float2*)(points + (size_t)b * NPT * 2);
    for (int p = t; p < NPT; p += 256) pts[p] = pb[p];
    __syncthreads();

    const int p0 = pc * 32;

    float4 mn = make_float4(3.4e38f, 3.4e38f, 3.4e38f, 3.4e38f);
    float4 sm = make_float4(0.f, 0.f, 0.f, 0.f);
    #pragma unroll 4
    for (int k = 0; k < 32; ++k) {
        float2 xy = pts[p0 + k];
        float dy  = xy.y - cy;
        float dy2 = dy * dy;
        float dx0 = xy.x - cx0, dx1 = xy.x - cx1, dx2 = xy.x - cx2, dx3 = xy.x - cx3;
        float d0 = fmaf(dx0, dx0, dy2);
        float d1 = fmaf(dx1, dx1, dy2);
        float d2 = fmaf(dx2, dx2, dy2);
        float d3 = fmaf(dx3, dx3, dy2);
        mn.x = fminf(mn.x, d0); mn.y = fminf(mn.y, d1);
        mn.z = fminf(mn.z, d2); mn.w = fminf(mn.w, d3);
        sm.x += exp2f(d0 * CEXP); sm.y += exp2f(d1 * CEXP);
        sm.z += exp2f(d2 * CEXP); sm.w += exp2f(d3 * CEXP);
    }

    #pragma unroll
    for (int off = 16; off <= 32; off <<= 1) {
        mn.x = fminf(mn.x, __shfl_xor(mn.x, off));
        mn.y = fminf(mn.y, __shfl_xor(mn.y, off));
        mn.z = fminf(mn.z, __shfl_xor(mn.z, off));
        mn.w = fminf(mn.w, __shfl_xor(mn.w, off));
        sm.x += __shfl_xor(sm.x, off);
        sm.y += __shfl_xor(sm.y, off);
        sm.z += __shfl_xor(sm.z, off);
        sm.w += __shfl_xor(sm.w, off);
    }
    if (lane < 16) { redmin[w][lane] = mn; redsum[w][lane] = sm; }
    __syncthreads();

    if (t < C) {
        const float* rm = (const float*)redmin;   // [4][64] floats
        const float* rq = (const float*)redsum;
        float m0 = fminf(fminf(rm[t], rm[64 + t]), fminf(rm[128 + t], rm[192 + t]));
        float s0 = (rq[t] + rq[64 + t]) + (rq[128 + t] + rq[192 + t]);
        float ss = st[b] * BG_RATIO;
        float bg = (ss * ss) / (m0 + EPS);
        float eb = exp2f(bg * CEXP);
        float r  = 1.0f / (s0 + eb);
        rsws[(size_t)b * M + i * C + t] = r;
        out[(size_t)b * NP1 * M + (size_t)NPT * M + i * C + t] = eb * r;
    }
}

// ---------------- Kernel 2: sequential streaming writer ----------------
// One block per (b, p) point-row: writes the row's 16 KB fully contiguously.
// Store group g: lane l writes float4 at m = g*1024 + 4*(wave*64+l) ->
// each wave-store is 1 KB sequential; block covers [0, 4096).
__global__ __launch_bounds__(256) void pp_store(
    const float* __restrict__ points,   // [B, NPT, 2]
    const float* __restrict__ rsws,     // [B, M]
    float* __restrict__ out)            // [B, NP1, M]
{
    const int b = blockIdx.x >> 9;
    const int p = blockIdx.x & 511;
    const int t = threadIdx.x;

    const float2 xy = ((const float2*)points)[b * NPT + p];
    const float* rrow = rsws + (size_t)b * M;
    float* orow = out + ((size_t)b * NP1 + p) * M;

    #pragma unroll
    for (int g = 0; g < 4; ++g) {
        const int m = g * 1024 + t * 4;
        const int i = m >> 6;
        const int j = m & 63;
        float dy  = xy.y - (float)(i * 8 + 4);
        float dy2 = dy * dy;
        float4 r4 = *(const float4*)(rrow + m);
        float dx0 = xy.x - (float)(j * 8 + 4);
        float dx1 = dx0 - 8.0f, dx2 = dx0 - 16.0f, dx3 = dx0 - 24.0f;
        float4 v;
        v.x = exp2f(fmaf(dx0, dx0, dy2) * CEXP) * r4.x;
        v.y = exp2f(fmaf(dx1, dx1, dy2) * CEXP) * r4.y;
        v.z = exp2f(fmaf(dx2, dx2, dy2) * CEXP) * r4.z;
        v.w = exp2f(fmaf(dx3, dx3, dy2) * CEXP) * r4.w;
        *(float4*)(orow + m) = v;
    }
}

extern "C" void kernel_launch(void* const* d_in, const int* in_sizes, int n_in,
                              void* d_out, int out_size, void* d_ws, size_t ws_size,
                              hipStream_t stream) {
    const float* points = (const float*)d_in[0];   // [16, 512, 2] fp32
    const float* st     = (const float*)d_in[1];   // [16] fp32
    float* out          = (float*)d_out;           // [16, 513, 4096] fp32
    float* rsws         = (float*)d_ws;            // [16, 4096] fp32 (256 KB)

    const int B = in_sizes[1];                     // 16
    pp_denom<<<dim3(B * C), dim3(256), 0, stream>>>(points, st, out, rsws);
    pp_store<<<dim3(B * NPT), dim3(256), 0, stream>>>(points, rsws, out);
}